// Round 5
// baseline (1127.675 us; speedup 1.0000x reference)
//
#include <hip/hip_runtime.h>
#include <hip/hip_bf16.h>
#include <cmath>
#include <stdint.h>

#define B_SZ 8
#define S_LEN 1024
#define T_LEN (B_SZ * S_LEN)   // 8192
#define HID 2560
#define NH 32
#define DH 80
#define ROT 40
#define RHALF 20
#define DP 96                  // padded head dim for Q/K (3 x 32)
#define NQKV 7680              // (32 + 64) * 80
#define SCALE 0.08838834764831844f  // 1/sqrt(128)

typedef unsigned short u16;
typedef short bf16x8 __attribute__((ext_vector_type(8)));
typedef float f32x4 __attribute__((ext_vector_type(4)));

#define AS1C(p) ((const __attribute__((address_space(1))) void*)(p))
#define AS3(p)  ((__attribute__((address_space(3))) void*)(p))

__device__ inline u16 f2b(float f) {
  __hip_bfloat16 h = __float2bfloat16(f);
  return __builtin_bit_cast(unsigned short, h);
}
__device__ inline float b2f(u16 u) {
  return __bfloat162float(__builtin_bit_cast(__hip_bfloat16, u));
}

// ---------------- fp32 -> bf16 cast (vectorized, grid-stride) ----------------
__global__ void cast_bf16_kernel(const float* __restrict__ x, u16* __restrict__ y, int n4) {
  int stride = gridDim.x * blockDim.x;
  for (int i = blockIdx.x * blockDim.x + threadIdx.x; i < n4; i += stride) {
    float4 v = ((const float4*)x)[i];
    u16 a = f2b(v.x), b = f2b(v.y), c = f2b(v.z), d = f2b(v.w);
    uint2 o;
    o.x = (unsigned)a | ((unsigned)b << 16);
    o.y = (unsigned)c | ((unsigned)d << 16);
    ((uint2*)y)[i] = o;
  }
}

// ---------------- GEMM: C[M,N] = A[M,K] * Bm[N,K]^T + bias ----------------
// ROUND-2 SCHEDULE RESTORED (measured 330 us QKV, MfmaUtil 43.3, FETCH 483MB).
// 256x256 tile, BK=64, 8 waves (2M x 4N), 512 threads, 128 KiB STATIC LDS.
// Staging spread one half-tile per phase (m201 pattern), counted vmcnt(4).
// Round-4 A/B showed: bunching all staging into p3/p4 with vmcnt(8) LOSES
// ~4% (344 us / 41.3) vs this staggered form — issue-spread beats prefetch
// depth. XCD swizzle measured HARMFUL (round 3: FETCH +28%). Plain mapping.
//
// Ledger (loads, 2 per STAGE): at tile k p4 after STAGE_A(k+2,0):
// outstanding = A1(k+1),B1(k+1),B0(k+2),A0(k+2) = 8 loads (4 instr-pairs);
// vmcnt(4) retires everything older => all of tile k+1 landed before any
// p1 ds_read of buf[(k+1)&1]; in-order retire + closing barrier publishes.
// WAR: each region's reads retire (lgkmcnt(0)+barrier) >=1 phase before its
// overwriter is issued. Tail: kt=NT-2/NT-1 drain vmcnt(0), stage nothing.
template<int OUT_BF16>
__global__ __launch_bounds__(512, 2) void gemm256_kernel(
    const u16* __restrict__ A, const u16* __restrict__ Bm,
    const float* __restrict__ bias, void* __restrict__ Cv,
    int M, int N, int K)
{
  // static 128 KiB LDS (gfx950 HW limit 160 KiB/WG)
  __shared__ __align__(16) u16 smem[65536];
  u16* As = smem;            // [buf][half][128*64] = 4 x 8192 u16
  u16* Bs = smem + 32768;    // same
  const int NT = K >> 6;

  int tid = threadIdx.x, w = tid >> 6, lane = tid & 63;
  int wm = w >> 2;           // 0..1: which 128-row half of C this wave owns
  int wn = w & 3;            // 0..3: which 64-col slice
  int col = lane & 15, quad = lane >> 4;
  int mb = blockIdx.y << 8, nb = blockIdx.x << 8;

  // staging: wave w fills chunks 2w, 2w+1 of each half-tile (chunk = 8 rows x
  // 64 cols = 1 KB = 64 lanes x 16B). Source-side XOR swizzle.
  int rr = lane >> 3;                 // row within chunk (== row&7)
  int swu = (lane & 7) ^ rr;          // swizzled source unit
  int c0 = __builtin_amdgcn_readfirstlane(2 * w);
  const u16* aP = A + (size_t)(mb + 16 * w + rr) * K + 8 * swu;
  const u16* bP = Bm + (size_t)(nb + 16 * w + rr) * K + 8 * swu;

  // fragment reads: row&7 == col&7 for every fragment row we touch
  int rxor = col & 7;
  int u0 = (quad ^ rxor) * 8;         // k-half 0, swizzled elem offset
  int u1 = ((quad + 4) ^ rxor) * 8;   // k-half 1
  const u16* aBase0 = As + wm * 8192 + col * 64;
  const u16* bBase0 = Bs + (wn >> 1) * 8192 + ((wn & 1) * 64 + col) * 64;

  f32x4 acc[8][4];
  const f32x4 fz = {0.f, 0.f, 0.f, 0.f};
#pragma unroll
  for (int i = 0; i < 8; i++)
#pragma unroll
    for (int j = 0; j < 4; j++) acc[i][j] = fz;

#define STAGE_A(kt, h) do { \
    const u16* _s = aP + (size_t)(h) * 128 * K + (size_t)(kt) * 64; \
    u16* _d = As + (((kt) & 1) * 2 + (h)) * 8192 + c0 * 512; \
    __builtin_amdgcn_global_load_lds(AS1C(_s), AS3(_d), 16, 0, 0); \
    __builtin_amdgcn_global_load_lds(AS1C(_s + 8 * (size_t)K), AS3(_d + 512), 16, 0, 0); \
  } while (0)
#define STAGE_B(kt, h) do { \
    const u16* _s = bP + (size_t)(h) * 128 * K + (size_t)(kt) * 64; \
    u16* _d = Bs + (((kt) & 1) * 2 + (h)) * 8192 + c0 * 512; \
    __builtin_amdgcn_global_load_lds(AS1C(_s), AS3(_d), 16, 0, 0); \
    __builtin_amdgcn_global_load_lds(AS1C(_s + 8 * (size_t)K), AS3(_d + 512), 16, 0, 0); \
  } while (0)

  // prologue: tile0 complete + tile1 {B0, A0}  (12 loads/thread)
  STAGE_A(0, 0); STAGE_A(0, 1); STAGE_B(0, 0); STAGE_B(0, 1);
  STAGE_B(1, 0); STAGE_A(1, 0);
  asm volatile("s_waitcnt vmcnt(4)" ::: "memory");   // tile0 landed; tile1 B0/A0 in flight
  __builtin_amdgcn_s_barrier();

  bf16x8 af[4][2];    // A frags of current m-quadrant (m0-3 then m4-7)
  bf16x8 bfv[4][2];   // B frags n0-3, persist across the K-tile

  for (int kt = 0; kt < NT; kt++) {
    const int buf = kt & 1;
    const u16* aB = aBase0 + buf * 16384;
    const u16* bB = bBase0 + buf * 16384;

    // ---- phase 1: read A m0-3 + B n0-1 (12 ds_read); stage (kt+1).A1 ----
#pragma unroll
    for (int mi = 0; mi < 4; mi++) {
      af[mi][0] = *(const bf16x8*)(aB + mi * 1024 + u0);
      af[mi][1] = *(const bf16x8*)(aB + mi * 1024 + u1);
    }
#pragma unroll
    for (int ni = 0; ni < 2; ni++) {
      bfv[ni][0] = *(const bf16x8*)(bB + ni * 1024 + u0);
      bfv[ni][1] = *(const bf16x8*)(bB + ni * 1024 + u1);
    }
    if (kt + 1 < NT) STAGE_A(kt + 1, 1);
    __builtin_amdgcn_s_barrier();
    asm volatile("s_waitcnt lgkmcnt(0)" ::: "memory");
    __builtin_amdgcn_s_setprio(1);
#pragma unroll
    for (int mi = 0; mi < 4; mi++)
#pragma unroll
      for (int ni = 0; ni < 2; ni++)
#pragma unroll
        for (int kh = 0; kh < 2; kh++)
          acc[mi][ni] = __builtin_amdgcn_mfma_f32_16x16x32_bf16(af[mi][kh], bfv[ni][kh], acc[mi][ni], 0, 0, 0);
    __builtin_amdgcn_s_setprio(0);
    __builtin_amdgcn_s_barrier();

    // ---- phase 2: read B n2-3 (4 ds_read); stage (kt+1).B1 ----
#pragma unroll
    for (int ni = 2; ni < 4; ni++) {
      bfv[ni][0] = *(const bf16x8*)(bB + ni * 1024 + u0);
      bfv[ni][1] = *(const bf16x8*)(bB + ni * 1024 + u1);
    }
    if (kt + 1 < NT) STAGE_B(kt + 1, 1);
    __builtin_amdgcn_s_barrier();
    asm volatile("s_waitcnt lgkmcnt(0)" ::: "memory");
    __builtin_amdgcn_s_setprio(1);
#pragma unroll
    for (int mi = 0; mi < 4; mi++)
#pragma unroll
      for (int ni = 2; ni < 4; ni++)
#pragma unroll
        for (int kh = 0; kh < 2; kh++)
          acc[mi][ni] = __builtin_amdgcn_mfma_f32_16x16x32_bf16(af[mi][kh], bfv[ni][kh], acc[mi][ni], 0, 0, 0);
    __builtin_amdgcn_s_setprio(0);
    __builtin_amdgcn_s_barrier();

    // ---- phase 3: read A m4-7 (8 ds_read); stage (kt+2).B0 (B fully read @p2) ----
#pragma unroll
    for (int mi = 0; mi < 4; mi++) {
      af[mi][0] = *(const bf16x8*)(aB + (mi + 4) * 1024 + u0);
      af[mi][1] = *(const bf16x8*)(aB + (mi + 4) * 1024 + u1);
    }
    if (kt + 2 < NT) STAGE_B(kt + 2, 0);
    __builtin_amdgcn_s_barrier();
    asm volatile("s_waitcnt lgkmcnt(0)" ::: "memory");
    __builtin_amdgcn_s_setprio(1);
#pragma unroll
    for (int mi = 0; mi < 4; mi++)
#pragma unroll
      for (int ni = 0; ni < 2; ni++)
#pragma unroll
        for (int kh = 0; kh < 2; kh++)
          acc[4 + mi][ni] = __builtin_amdgcn_mfma_f32_16x16x32_bf16(af[mi][kh], bfv[ni][kh], acc[4 + mi][ni], 0, 0, 0);
    __builtin_amdgcn_s_setprio(0);
    __builtin_amdgcn_s_barrier();

    // ---- phase 4: stage (kt+2).A0 (A fully read @p3); counted vmcnt ----
    if (kt + 2 < NT) {
      STAGE_A(kt + 2, 0);
      asm volatile("s_waitcnt vmcnt(4)" ::: "memory");   // tile kt+1 landed; kt+2 B0/A0 in flight
    } else {
      asm volatile("s_waitcnt vmcnt(0)" ::: "memory");   // tail drain (kt = NT-2, NT-1)
    }
    __builtin_amdgcn_s_barrier();
    __builtin_amdgcn_s_setprio(1);
#pragma unroll
    for (int mi = 0; mi < 4; mi++)
#pragma unroll
      for (int ni = 2; ni < 4; ni++)
#pragma unroll
        for (int kh = 0; kh < 2; kh++)
          acc[4 + mi][ni] = __builtin_amdgcn_mfma_f32_16x16x32_bf16(af[mi][kh], bfv[ni][kh], acc[4 + mi][ni], 0, 0, 0);
    __builtin_amdgcn_s_setprio(0);
    __builtin_amdgcn_s_barrier();
  }
#undef STAGE_A
#undef STAGE_B

  // epilogue
#pragma unroll
  for (int ni = 0; ni < 4; ni++) {
    int n = nb + wn * 64 + ni * 16 + col;
    float bv = bias[n];
#pragma unroll
    for (int mi = 0; mi < 8; mi++) {
      int mrow = mb + wm * 128 + mi * 16 + quad * 4;
#pragma unroll
      for (int r = 0; r < 4; r++) {
        float v = acc[mi][ni][r] + bv;
        if (OUT_BF16)
          ((u16*)Cv)[(size_t)(mrow + r) * N + n] = f2b(v);
        else
          ((float*)Cv)[(size_t)(mrow + r) * N + n] = v;
      }
    }
  }
}

// ---------------- RoPE on Q,K; writes padded [bh][s][96] layouts ----------------
__global__ void rope_qk_kernel(const u16* __restrict__ qkv,
                               const float* __restrict__ cosd,
                               const float* __restrict__ sind,
                               u16* __restrict__ Q96, u16* __restrict__ K96) {
  int t = blockIdx.x;
  int b = t >> 10, s = t & 1023;
  __shared__ float cs[RHALF], sn[RHALF];
  int tid = threadIdx.x;
  if (tid < RHALF) cs[tid] = cosd[t * RHALF + tid];
  else if (tid < 2 * RHALF) sn[tid - RHALF] = sind[t * RHALF + (tid - RHALF)];
  __syncthreads();
  for (int i = tid; i < 2 * NH * DP; i += 256) {
    int sel = (i >= NH * DP) ? 1 : 0;
    int ii = i - sel * NH * DP;
    int hh = ii / DP, d = ii - hh * DP;
    const u16* src = qkv + (size_t)t * NQKV + sel * HID + hh * DH;
    float v;
    if (d < RHALF)      v = b2f(src[d]) * cs[d] - b2f(src[d + RHALF]) * sn[d];
    else if (d < ROT)   v = b2f(src[d]) * cs[d - RHALF] + b2f(src[d - RHALF]) * sn[d - RHALF];
    else if (d < DH)    v = b2f(src[d]);
    else                v = 0.f;
    if (!sel) v *= SCALE;   // pre-scale Q so scores come out scaled
    u16* dst = sel ? K96 : Q96;
    dst[((size_t)(b * NH + hh) * S_LEN + s) * DP + d] = f2b(v);
  }
}

// ---------------- V transpose: qkv v-part -> Vt[bh][80][1024] ----------------
__global__ void v_trans_kernel(const u16* __restrict__ qkv, u16* __restrict__ Vt) {
  int blk = blockIdx.x;
  int st = blk & 15, bh = blk >> 4;
  int b = bh >> 5, h = bh & 31;
  int s0 = st * 64;
  __shared__ __align__(16) u16 tile[64][88];
  int tid = threadIdx.x;
  for (int c = tid; c < 640; c += 256) {           // 64 rows x 10 chunks of 8
    int r = c / 10, cc = c - (c / 10) * 10;
    *(uint4*)&tile[r][cc * 8] =
        *(const uint4*)(qkv + (size_t)(b * S_LEN + s0 + r) * NQKV + 2 * HID + h * DH + cc * 8);
  }
  __syncthreads();
  for (int i = tid; i < 5120; i += 256) {          // 80 dims x 64 tokens
    int d = i >> 6, ss = i & 63;
    Vt[((size_t)bh * DH + d) * S_LEN + s0 + ss] = tile[ss][d];
  }
}

// ---------------- causal flash attention (v3: T14 async-STAGE) ----------------
// grid (S/128, B*H); 4 waves; each wave owns 32 Q rows (2 MFMA m-groups).
// No online max (scores bounded; clamp 30 as NaN guard). l via ones-row.
// T14: next tile's K/V global loads issued into REGISTERS before compute
// (latency hides under ~48 MFMA), ds_write to LDS after the post-compute
// barrier. Same 2 barriers/tile as before; +24 VGPR (6x uint4 in flight).
__global__ __launch_bounds__(256) void flash_kernel(
    const u16* __restrict__ Q, const u16* __restrict__ K,
    const u16* __restrict__ Vt, u16* __restrict__ Oo) {
  int qt = blockIdx.x, bh = blockIdx.y;
  int b = bh >> 5, h = bh & 31;
  int tid = threadIdx.x, w = tid >> 6, lane = tid & 63;
  int col = lane & 15, quad = lane >> 4;
  int qw = qt * 128 + w * 32;            // wave's first Q row within this bh

  __shared__ __align__(16) u16 Ks[64][104];   // 64 keys x 96 dims (pad 104)
  __shared__ __align__(16) u16 Vs[96][72];    // dims 0..79 = V, 80 = ones, 81..95 = 0
  __shared__ __align__(16) u16 Ps[4][32][72]; // per-wave P tile, 32 rows x 64 keys

  // constant V-extension rows (staging only ever rewrites rows 0..79)
  for (int i = tid; i < 16 * 64; i += 256) {
    int r = 80 + (i >> 6), k = i & 63;
    Vs[r][k] = (r == 80) ? (u16)0x3F80 : (u16)0;  // bf16 1.0 / 0.0
  }

  bf16x8 qf[2][3];
#pragma unroll
  for (int m = 0; m < 2; m++) {
    const u16* qrow = Q + ((size_t)bh * S_LEN + qw + m * 16 + col) * DP;
#pragma unroll
    for (int kk = 0; kk < 3; kk++)
      qf[m][kk] = *(const bf16x8*)(qrow + kk * 32 + quad * 8);
  }
  const f32x4 fz = {0.f, 0.f, 0.f, 0.f};
  f32x4 o[2][6];
#pragma unroll
  for (int m = 0; m < 2; m++)
#pragma unroll
    for (int n = 0; n < 6; n++) o[m][n] = fz;

  const u16* kbase0 = K + (size_t)bh * S_LEN * DP;
  const u16* vbase0 = Vt + (size_t)bh * DH * S_LEN;
  int nt = 2 * qt + 2;

  // T14 reg-staging setup: 768 K-uint4s (3/thread) + 640 V-uint4s (2.5/thread)
  uint4 rK[3], rV[3];
  int kr[3], kc[3], vd[3], vc[3];
#pragma unroll
  for (int i = 0; i < 3; i++) {
    int c = tid + 256 * i;
    kr[i] = c / 12; kc[i] = c - kr[i] * 12;
    vd[i] = c >> 3; vc[i] = c & 7;
  }
  const bool v2ok = (tid + 512) < 640;

#define LDKV(kt_) do { \
    const u16* kb_ = kbase0 + (size_t)(kt_) * 64 * DP; \
    rK[0] = *(const uint4*)(kb_ + kr[0] * DP + kc[0] * 8); \
    rK[1] = *(const uint4*)(kb_ + kr[1] * DP + kc[1] * 8); \
    rK[2] = *(const uint4*)(kb_ + kr[2] * DP + kc[2] * 8); \
    const u16* vb_ = vbase0 + (size_t)(kt_) * 64; \
    rV[0] = *(const uint4*)(vb_ + (size_t)vd[0] * S_LEN + vc[0] * 8); \
    rV[1] = *(const uint4*)(vb_ + (size_t)vd[1] * S_LEN + vc[1] * 8); \
    if (v2ok) rV[2] = *(const uint4*)(vb_ + (size_t)vd[2] * S_LEN + vc[2] * 8); \
  } while (0)
#define WRKV() do { \
    *(uint4*)&Ks[kr[0]][kc[0] * 8] = rK[0]; \
    *(uint4*)&Ks[kr[1]][kc[1] * 8] = rK[1]; \
    *(uint4*)&Ks[kr[2]][kc[2] * 8] = rK[2]; \
    *(uint4*)&Vs[vd[0]][vc[0] * 8] = rV[0]; \
    *(uint4*)&Vs[vd[1]][vc[1] * 8] = rV[1]; \
    if (v2ok) *(uint4*)&Vs[vd[2]][vc[2] * 8] = rV[2]; \
  } while (0)

  // prologue: tile 0 staged (compiler inserts vmcnt waits before ds_writes)
  LDKV(0);
  WRKV();
  __syncthreads();

  for (int kt = 0; kt < nt; kt++) {
    if (kt + 1 < nt) LDKV(kt + 1);   // issue next-tile loads; hide under compute
    int k0 = kt * 64;
    if (k0 <= qw + 31) {          // wave has at least one unmasked key
#pragma unroll
      for (int m = 0; m < 2; m++) {
        int rowbase = qw + m * 16;
        f32x4 s[4];
#pragma unroll
        for (int n = 0; n < 4; n++) {
          f32x4 acc = fz;
#pragma unroll
          for (int kk = 0; kk < 3; kk++) {
            bf16x8 kf = *(const bf16x8*)&Ks[n * 16 + col][kk * 32 + quad * 8];
            acc = __builtin_amdgcn_mfma_f32_16x16x32_bf16(qf[m][kk], kf, acc, 0, 0, 0);
          }
          s[n] = acc;
        }
        if (k0 + 63 > rowbase) {  // diagonal: causal mask needed for this m-group
#pragma unroll
          for (int n = 0; n < 4; n++) {
            int key = k0 + n * 16 + col;
#pragma unroll
            for (int r = 0; r < 4; r++)
              if (key > rowbase + quad * 4 + r) s[n][r] = -INFINITY;
          }
        }
#pragma unroll
        for (int n = 0; n < 4; n++)
#pragma unroll
          for (int r = 0; r < 4; r++) {
            float p = __expf(fminf(s[n][r], 30.f));
            Ps[w][m * 16 + quad * 4 + r][n * 16 + col] = f2b(p);
          }
      }
      asm volatile("s_waitcnt lgkmcnt(0)" ::: "memory");  // own P writes visible
      // O += P V  (dim 80 accumulates l via ones row)
#pragma unroll
      for (int m = 0; m < 2; m++)
#pragma unroll
        for (int kk = 0; kk < 2; kk++) {
          bf16x8 pf = *(const bf16x8*)&Ps[w][m * 16 + col][kk * 32 + quad * 8];
#pragma unroll
          for (int n2 = 0; n2 < 6; n2++) {
            bf16x8 vf = *(const bf16x8*)&Vs[n2 * 16 + col][kk * 32 + quad * 8];
            o[m][n2] = __builtin_amdgcn_mfma_f32_16x16x32_bf16(pf, vf, o[m][n2], 0, 0, 0);
          }
        }
    }
    __syncthreads();                 // all compute reads of Ks/Vs done
    if (kt + 1 < nt) WRKV();         // land prefetched tile (vmcnt auto-waited)
    __syncthreads();                 // writes visible to all waves
  }
#undef LDKV
#undef WRKV

  // epilogue: l lives at dim-80 column (n2=5, col=0 lane of each quad group)
  int src = lane & 48;
#pragma unroll
  for (int m = 0; m < 2; m++)
#pragma unroll
    for (int r = 0; r < 4; r++) {
      float l = __shfl(o[m][5][r], src);
      float inv = 1.f / l;
      int t = b * S_LEN + qw + m * 16 + quad * 4 + r;
#pragma unroll
      for (int n2 = 0; n2 < 5; n2++)
        Oo[(size_t)t * HID + h * DH + n2 * 16 + col] = f2b(o[m][n2][r] * inv);
    }
}

extern "C" void kernel_launch(void* const* d_in, const int* in_sizes, int n_in,
                              void* d_out, int out_size, void* d_ws, size_t ws_size,
                              hipStream_t stream) {
  const float* hidden  = (const float*)d_in[0];
  const float* cosd    = (const float*)d_in[1];
  const float* sind    = (const float*)d_in[2];
  const float* w_qkv   = (const float*)d_in[3];
  const float* b_qkv   = (const float*)d_in[4];
  const float* w_dense = (const float*)d_in[5];
  const float* b_dense = (const float*)d_in[6];
  float* out = (float*)d_out;

  // workspace layout (regions reused across phase boundaries):
  //  A: [0, 81.3MB)  = hid_bf + wqkv_bf, later reused as Q96
  //  B: [81.3, 207.1MB) = qkv_bf, later reused as attn_bf + wdense_bf
  //  C: [207.1, 257.4MB) = K96
  //  D: [257.4, 299.4MB) = Vt
  char* ws = (char*)d_ws;
  u16* hid_bf    = (u16*)(ws);
  u16* wqkv_bf   = (u16*)(ws + 41943040ull);
  u16* Q96       = (u16*)(ws);                                 // reuses A
  u16* qkv_bf    = (u16*)(ws + 81264640ull);
  u16* attn_bf   = (u16*)(ws + 81264640ull);                   // reuses B
  u16* wdense_bf = (u16*)(ws + 81264640ull + 41943040ull);     // reuses B tail
  u16* K96       = (u16*)(ws + 81264640ull + 125829120ull);
  u16* Vt        = (u16*)(ws + 81264640ull + 125829120ull + 50331648ull);

  cast_bf16_kernel<<<2048, 256, 0, stream>>>(hidden, hid_bf, T_LEN * HID / 4);
  cast_bf16_kernel<<<2048, 256, 0, stream>>>(w_qkv, wqkv_bf, NQKV * HID / 4);
  gemm256_kernel<1><<<dim3(NQKV / 256, T_LEN / 256), 512, 0, stream>>>(
      hid_bf, wqkv_bf, b_qkv, qkv_bf, T_LEN, NQKV, HID);
  rope_qk_kernel<<<T_LEN, 256, 0, stream>>>(qkv_bf, cosd, sind, Q96, K96);
  v_trans_kernel<<<4096, 256, 0, stream>>>(qkv_bf, Vt);
  flash_kernel<<<dim3(8, 256), 256, 0, stream>>>(Q96, K96, Vt, attn_bf);
  cast_bf16_kernel<<<512, 256, 0, stream>>>(w_dense, wdense_bf, HID * HID / 4);
  gemm256_kernel<0><<<dim3(HID / 256, T_LEN / 256), 512, 0, stream>>>(
      attn_bf, wdense_bf, b_dense, out, T_LEN, HID, HID);
}

// Round 7
// 1024.744 us; speedup vs baseline: 1.1004x; 1.1004x over previous
//
#include <hip/hip_runtime.h>
#include <hip/hip_bf16.h>
#include <cmath>
#include <stdint.h>

#define B_SZ 8
#define S_LEN 1024
#define T_LEN (B_SZ * S_LEN)   // 8192
#define HID 2560
#define NH 32
#define DH 80
#define ROT 40
#define RHALF 20
#define DP 96                  // padded head dim for Q/K (3 x 32)
#define NQKV 7680              // (32 + 64) * 80
#define SCALE 0.08838834764831844f  // 1/sqrt(128)

typedef unsigned short u16;
typedef short bf16x8 __attribute__((ext_vector_type(8)));
typedef float f32x4 __attribute__((ext_vector_type(4)));

#define AS1C(p) ((const __attribute__((address_space(1))) void*)(p))
#define AS3(p)  ((__attribute__((address_space(3))) void*)(p))

__device__ inline u16 f2b(float f) {
  __hip_bfloat16 h = __float2bfloat16(f);
  return __builtin_bit_cast(unsigned short, h);
}
__device__ inline float b2f(u16 u) {
  return __bfloat162float(__builtin_bit_cast(__hip_bfloat16, u));
}

// ---------------- fp32 -> bf16 cast (vectorized, grid-stride) ----------------
__global__ void cast_bf16_kernel(const float* __restrict__ x, u16* __restrict__ y, int n4) {
  int stride = gridDim.x * blockDim.x;
  for (int i = blockIdx.x * blockDim.x + threadIdx.x; i < n4; i += stride) {
    float4 v = ((const float4*)x)[i];
    u16 a = f2b(v.x), b = f2b(v.y), c = f2b(v.z), d = f2b(v.w);
    uint2 o;
    o.x = (unsigned)a | ((unsigned)b << 16);
    o.y = (unsigned)c | ((unsigned)d << 16);
    ((uint2*)y)[i] = o;
  }
}

// ---------------- GEMM: C[M,N] = A[M,K] * Bm[N,K]^T + bias ----------------
// ROUND-2 SCHEDULE (best measured: QKV 330 us, MfmaUtil 43.3, FETCH 483MB).
// 256x256 tile, BK=64, 8 waves (2M x 4N), 512 threads, 128 KiB STATIC LDS.
// Staging spread one half-tile per phase (m201 pattern), counted vmcnt(4).
// A/B history: bunched staging + vmcnt(8) = -4% (round 4); XCD swizzle =
// FETCH +28%, -5% (round 3). Plain block mapping, staggered staging. Do not
// re-try those.
//
// Ledger: at tile k p4 after STAGE_A(k+2,0): outstanding = A1(k+1),B1(k+1),
// B0(k+2),A0(k+2) = 8 loads; vmcnt(4) retires tile k+1 fully before any p1
// ds_read of buf[(k+1)&1]; in-order retire + closing barrier publishes.
// WAR: each region's reads retire (lgkmcnt(0)+barrier) >=1 phase before its
// overwriter is issued. Tail: kt=NT-2/NT-1 drain vmcnt(0), stage nothing.
template<int OUT_BF16>
__global__ __launch_bounds__(512, 2) void gemm256_kernel(
    const u16* __restrict__ A, const u16* __restrict__ Bm,
    const float* __restrict__ bias, void* __restrict__ Cv,
    int M, int N, int K)
{
  // static 128 KiB LDS (gfx950 HW limit 160 KiB/WG)
  __shared__ __align__(16) u16 smem[65536];
  u16* As = smem;            // [buf][half][128*64] = 4 x 8192 u16
  u16* Bs = smem + 32768;    // same
  const int NT = K >> 6;

  int tid = threadIdx.x, w = tid >> 6, lane = tid & 63;
  int wm = w >> 2;           // 0..1: which 128-row half of C this wave owns
  int wn = w & 3;            // 0..3: which 64-col slice
  int col = lane & 15, quad = lane >> 4;
  int mb = blockIdx.y << 8, nb = blockIdx.x << 8;

  // staging: wave w fills chunks 2w, 2w+1 of each half-tile (chunk = 8 rows x
  // 64 cols = 1 KB = 64 lanes x 16B). Source-side XOR swizzle.
  int rr = lane >> 3;                 // row within chunk (== row&7)
  int swu = (lane & 7) ^ rr;          // swizzled source unit
  int c0 = __builtin_amdgcn_readfirstlane(2 * w);
  const u16* aP = A + (size_t)(mb + 16 * w + rr) * K + 8 * swu;
  const u16* bP = Bm + (size_t)(nb + 16 * w + rr) * K + 8 * swu;

  // fragment reads: row&7 == col&7 for every fragment row we touch
  int rxor = col & 7;
  int u0 = (quad ^ rxor) * 8;         // k-half 0, swizzled elem offset
  int u1 = ((quad + 4) ^ rxor) * 8;   // k-half 1
  const u16* aBase0 = As + wm * 8192 + col * 64;
  const u16* bBase0 = Bs + (wn >> 1) * 8192 + ((wn & 1) * 64 + col) * 64;

  f32x4 acc[8][4];
  const f32x4 fz = {0.f, 0.f, 0.f, 0.f};
#pragma unroll
  for (int i = 0; i < 8; i++)
#pragma unroll
    for (int j = 0; j < 4; j++) acc[i][j] = fz;

#define STAGE_A(kt, h) do { \
    const u16* _s = aP + (size_t)(h) * 128 * K + (size_t)(kt) * 64; \
    u16* _d = As + (((kt) & 1) * 2 + (h)) * 8192 + c0 * 512; \
    __builtin_amdgcn_global_load_lds(AS1C(_s), AS3(_d), 16, 0, 0); \
    __builtin_amdgcn_global_load_lds(AS1C(_s + 8 * (size_t)K), AS3(_d + 512), 16, 0, 0); \
  } while (0)
#define STAGE_B(kt, h) do { \
    const u16* _s = bP + (size_t)(h) * 128 * K + (size_t)(kt) * 64; \
    u16* _d = Bs + (((kt) & 1) * 2 + (h)) * 8192 + c0 * 512; \
    __builtin_amdgcn_global_load_lds(AS1C(_s), AS3(_d), 16, 0, 0); \
    __builtin_amdgcn_global_load_lds(AS1C(_s + 8 * (size_t)K), AS3(_d + 512), 16, 0, 0); \
  } while (0)

  // prologue: tile0 complete + tile1 {B0, A0}  (12 loads/thread)
  STAGE_A(0, 0); STAGE_A(0, 1); STAGE_B(0, 0); STAGE_B(0, 1);
  STAGE_B(1, 0); STAGE_A(1, 0);
  asm volatile("s_waitcnt vmcnt(4)" ::: "memory");   // tile0 landed; tile1 B0/A0 in flight
  __builtin_amdgcn_s_barrier();

  bf16x8 af[4][2];    // A frags of current m-quadrant (m0-3 then m4-7)
  bf16x8 bfv[4][2];   // B frags n0-3, persist across the K-tile

  for (int kt = 0; kt < NT; kt++) {
    const int buf = kt & 1;
    const u16* aB = aBase0 + buf * 16384;
    const u16* bB = bBase0 + buf * 16384;

    // ---- phase 1: read A m0-3 + B n0-1 (12 ds_read); stage (kt+1).A1 ----
#pragma unroll
    for (int mi = 0; mi < 4; mi++) {
      af[mi][0] = *(const bf16x8*)(aB + mi * 1024 + u0);
      af[mi][1] = *(const bf16x8*)(aB + mi * 1024 + u1);
    }
#pragma unroll
    for (int ni = 0; ni < 2; ni++) {
      bfv[ni][0] = *(const bf16x8*)(bB + ni * 1024 + u0);
      bfv[ni][1] = *(const bf16x8*)(bB + ni * 1024 + u1);
    }
    if (kt + 1 < NT) STAGE_A(kt + 1, 1);
    __builtin_amdgcn_s_barrier();
    asm volatile("s_waitcnt lgkmcnt(0)" ::: "memory");
    __builtin_amdgcn_s_setprio(1);
#pragma unroll
    for (int mi = 0; mi < 4; mi++)
#pragma unroll
      for (int ni = 0; ni < 2; ni++)
#pragma unroll
        for (int kh = 0; kh < 2; kh++)
          acc[mi][ni] = __builtin_amdgcn_mfma_f32_16x16x32_bf16(af[mi][kh], bfv[ni][kh], acc[mi][ni], 0, 0, 0);
    __builtin_amdgcn_s_setprio(0);
    __builtin_amdgcn_s_barrier();

    // ---- phase 2: read B n2-3 (4 ds_read); stage (kt+1).B1 ----
#pragma unroll
    for (int ni = 2; ni < 4; ni++) {
      bfv[ni][0] = *(const bf16x8*)(bB + ni * 1024 + u0);
      bfv[ni][1] = *(const bf16x8*)(bB + ni * 1024 + u1);
    }
    if (kt + 1 < NT) STAGE_B(kt + 1, 1);
    __builtin_amdgcn_s_barrier();
    asm volatile("s_waitcnt lgkmcnt(0)" ::: "memory");
    __builtin_amdgcn_s_setprio(1);
#pragma unroll
    for (int mi = 0; mi < 4; mi++)
#pragma unroll
      for (int ni = 2; ni < 4; ni++)
#pragma unroll
        for (int kh = 0; kh < 2; kh++)
          acc[mi][ni] = __builtin_amdgcn_mfma_f32_16x16x32_bf16(af[mi][kh], bfv[ni][kh], acc[mi][ni], 0, 0, 0);
    __builtin_amdgcn_s_setprio(0);
    __builtin_amdgcn_s_barrier();

    // ---- phase 3: read A m4-7 (8 ds_read); stage (kt+2).B0 (B fully read @p2) ----
#pragma unroll
    for (int mi = 0; mi < 4; mi++) {
      af[mi][0] = *(const bf16x8*)(aB + (mi + 4) * 1024 + u0);
      af[mi][1] = *(const bf16x8*)(aB + (mi + 4) * 1024 + u1);
    }
    if (kt + 2 < NT) STAGE_B(kt + 2, 0);
    __builtin_amdgcn_s_barrier();
    asm volatile("s_waitcnt lgkmcnt(0)" ::: "memory");
    __builtin_amdgcn_s_setprio(1);
#pragma unroll
    for (int mi = 0; mi < 4; mi++)
#pragma unroll
      for (int ni = 0; ni < 2; ni++)
#pragma unroll
        for (int kh = 0; kh < 2; kh++)
          acc[4 + mi][ni] = __builtin_amdgcn_mfma_f32_16x16x32_bf16(af[mi][kh], bfv[ni][kh], acc[4 + mi][ni], 0, 0, 0);
    __builtin_amdgcn_s_setprio(0);
    __builtin_amdgcn_s_barrier();

    // ---- phase 4: stage (kt+2).A0 (A fully read @p3); counted vmcnt ----
    if (kt + 2 < NT) {
      STAGE_A(kt + 2, 0);
      asm volatile("s_waitcnt vmcnt(4)" ::: "memory");   // tile kt+1 landed; kt+2 B0/A0 in flight
    } else {
      asm volatile("s_waitcnt vmcnt(0)" ::: "memory");   // tail drain (kt = NT-2, NT-1)
    }
    __builtin_amdgcn_s_barrier();
    __builtin_amdgcn_s_setprio(1);
#pragma unroll
    for (int mi = 0; mi < 4; mi++)
#pragma unroll
      for (int ni = 2; ni < 4; ni++)
#pragma unroll
        for (int kh = 0; kh < 2; kh++)
          acc[4 + mi][ni] = __builtin_amdgcn_mfma_f32_16x16x32_bf16(af[mi][kh], bfv[ni][kh], acc[4 + mi][ni], 0, 0, 0);
    __builtin_amdgcn_s_setprio(0);
    __builtin_amdgcn_s_barrier();
  }
#undef STAGE_A
#undef STAGE_B

  // epilogue
#pragma unroll
  for (int ni = 0; ni < 4; ni++) {
    int n = nb + wn * 64 + ni * 16 + col;
    float bv = bias[n];
#pragma unroll
    for (int mi = 0; mi < 8; mi++) {
      int mrow = mb + wm * 128 + mi * 16 + quad * 4;
#pragma unroll
      for (int r = 0; r < 4; r++) {
        float v = acc[mi][ni][r] + bv;
        if (OUT_BF16)
          ((u16*)Cv)[(size_t)(mrow + r) * N + n] = f2b(v);
        else
          ((float*)Cv)[(size_t)(mrow + r) * N + n] = v;
      }
    }
  }
}

// ---------------- RoPE on Q,K; writes padded [bh][s][96] layouts ----------------
__global__ void rope_qk_kernel(const u16* __restrict__ qkv,
                               const float* __restrict__ cosd,
                               const float* __restrict__ sind,
                               u16* __restrict__ Q96, u16* __restrict__ K96) {
  int t = blockIdx.x;
  int b = t >> 10, s = t & 1023;
  __shared__ float cs[RHALF], sn[RHALF];
  int tid = threadIdx.x;
  if (tid < RHALF) cs[tid] = cosd[t * RHALF + tid];
  else if (tid < 2 * RHALF) sn[tid - RHALF] = sind[t * RHALF + (tid - RHALF)];
  __syncthreads();
  for (int i = tid; i < 2 * NH * DP; i += 256) {
    int sel = (i >= NH * DP) ? 1 : 0;
    int ii = i - sel * NH * DP;
    int hh = ii / DP, d = ii - hh * DP;
    const u16* src = qkv + (size_t)t * NQKV + sel * HID + hh * DH;
    float v;
    if (d < RHALF)      v = b2f(src[d]) * cs[d] - b2f(src[d + RHALF]) * sn[d];
    else if (d < ROT)   v = b2f(src[d]) * cs[d - RHALF] + b2f(src[d - RHALF]) * sn[d - RHALF];
    else if (d < DH)    v = b2f(src[d]);
    else                v = 0.f;
    if (!sel) v *= SCALE;   // pre-scale Q so scores come out scaled
    u16* dst = sel ? K96 : Q96;
    dst[((size_t)(b * NH + hh) * S_LEN + s) * DP + d] = f2b(v);
  }
}

// ---------------- V transpose: qkv v-part -> Vt[bh][80][1024] ----------------
__global__ void v_trans_kernel(const u16* __restrict__ qkv, u16* __restrict__ Vt) {
  int blk = blockIdx.x;
  int st = blk & 15, bh = blk >> 4;
  int b = bh >> 5, h = bh & 31;
  int s0 = st * 64;
  __shared__ __align__(16) u16 tile[64][88];
  int tid = threadIdx.x;
  for (int c = tid; c < 640; c += 256) {           // 64 rows x 10 chunks of 8
    int r = c / 10, cc = c - (c / 10) * 10;
    *(uint4*)&tile[r][cc * 8] =
        *(const uint4*)(qkv + (size_t)(b * S_LEN + s0 + r) * NQKV + 2 * HID + h * DH + cc * 8);
  }
  __syncthreads();
  for (int i = tid; i < 5120; i += 256) {          // 80 dims x 64 tokens
    int d = i >> 6, ss = i & 63;
    Vt[((size_t)bh * DH + d) * S_LEN + s0 + ss] = tile[ss][d];
  }
}

// ---------------- causal flash attention (v2 — measured best) ----------------
// grid (S/128, B*H); 4 waves; each wave owns 32 Q rows (2 MFMA m-groups).
// No online max (scores bounded; clamp 30 as NaN guard) -> no cross-lane ops
// in the loop. l computed via ones-row (dim 80) appended to V in LDS.
// History: T14 reg-staging variant (round 5) = +100 us REGRESSION — flash is
// latency/LDS-bound (MfmaUtil 5.7%), no compute phase to hide loads under.
__global__ __launch_bounds__(256) void flash_kernel(
    const u16* __restrict__ Q, const u16* __restrict__ K,
    const u16* __restrict__ Vt, u16* __restrict__ Oo) {
  int qt = blockIdx.x, bh = blockIdx.y;
  int b = bh >> 5, h = bh & 31;
  int tid = threadIdx.x, w = tid >> 6, lane = tid & 63;
  int col = lane & 15, quad = lane >> 4;
  int qw = qt * 128 + w * 32;            // wave's first Q row within this bh

  __shared__ __align__(16) u16 Ks[64][104];   // 64 keys x 96 dims (pad 104)
  __shared__ __align__(16) u16 Vs[96][72];    // dims 0..79 = V, 80 = ones, 81..95 = 0
  __shared__ __align__(16) u16 Ps[4][32][72]; // per-wave P tile, 32 rows x 64 keys

  // constant V-extension rows (staging only ever rewrites rows 0..79)
  for (int i = tid; i < 16 * 64; i += 256) {
    int r = 80 + (i >> 6), k = i & 63;
    Vs[r][k] = (r == 80) ? (u16)0x3F80 : (u16)0;  // bf16 1.0 / 0.0
  }

  bf16x8 qf[2][3];
#pragma unroll
  for (int m = 0; m < 2; m++) {
    const u16* qrow = Q + ((size_t)bh * S_LEN + qw + m * 16 + col) * DP;
#pragma unroll
    for (int kk = 0; kk < 3; kk++)
      qf[m][kk] = *(const bf16x8*)(qrow + kk * 32 + quad * 8);
  }
  const f32x4 fz = {0.f, 0.f, 0.f, 0.f};
  f32x4 o[2][6];
#pragma unroll
  for (int m = 0; m < 2; m++)
#pragma unroll
    for (int n = 0; n < 6; n++) o[m][n] = fz;

  const u16* kbase0 = K + (size_t)bh * S_LEN * DP;
  const u16* vbase0 = Vt + (size_t)bh * DH * S_LEN;
  int nt = 2 * qt + 2;
  for (int kt = 0; kt < nt; kt++) {
    // stage K tile [64][96]
    const u16* kbase = kbase0 + kt * 64 * DP;
    for (int c = tid; c < 768; c += 256) {
      int r = c / 12, cc = c - (c / 12) * 12;
      *(uint4*)&Ks[r][cc * 8] = *(const uint4*)(kbase + r * DP + cc * 8);
    }
    // stage V tile [80][64]: 80 rows x 8 chunks of 8 = 640 uint4s
    const u16* vbase = vbase0 + kt * 64;
    for (int c = tid; c < 640; c += 256) {
      int d = c >> 3, cc = c & 7;
      *(uint4*)&Vs[d][cc * 8] = *(const uint4*)(vbase + (size_t)d * S_LEN + cc * 8);
    }
    __syncthreads();
    int k0 = kt * 64;
    if (k0 <= qw + 31) {          // wave has at least one unmasked key
#pragma unroll
      for (int m = 0; m < 2; m++) {
        int rowbase = qw + m * 16;
        f32x4 s[4];
#pragma unroll
        for (int n = 0; n < 4; n++) {
          f32x4 acc = fz;
#pragma unroll
          for (int kk = 0; kk < 3; kk++) {
            bf16x8 kf = *(const bf16x8*)&Ks[n * 16 + col][kk * 32 + quad * 8];
            acc = __builtin_amdgcn_mfma_f32_16x16x32_bf16(qf[m][kk], kf, acc, 0, 0, 0);
          }
          s[n] = acc;
        }
        if (k0 + 63 > rowbase) {  // diagonal: causal mask needed for this m-group
#pragma unroll
          for (int n = 0; n < 4; n++) {
            int key = k0 + n * 16 + col;
#pragma unroll
            for (int r = 0; r < 4; r++)
              if (key > rowbase + quad * 4 + r) s[n][r] = -INFINITY;
          }
        }
#pragma unroll
        for (int n = 0; n < 4; n++)
#pragma unroll
          for (int r = 0; r < 4; r++) {
            float p = __expf(fminf(s[n][r], 30.f));
            Ps[w][m * 16 + quad * 4 + r][n * 16 + col] = f2b(p);
          }
      }
      asm volatile("s_waitcnt lgkmcnt(0)" ::: "memory");  // own P writes visible
      // O += P V  (dim 80 accumulates l via ones row)
#pragma unroll
      for (int m = 0; m < 2; m++)
#pragma unroll
        for (int kk = 0; kk < 2; kk++) {
          bf16x8 pf = *(const bf16x8*)&Ps[w][m * 16 + col][kk * 32 + quad * 8];
#pragma unroll
          for (int n2 = 0; n2 < 6; n2++) {
            bf16x8 vf = *(const bf16x8*)&Vs[n2 * 16 + col][kk * 32 + quad * 8];
            o[m][n2] = __builtin_amdgcn_mfma_f32_16x16x32_bf16(pf, vf, o[m][n2], 0, 0, 0);
          }
        }
    }
    __syncthreads();
  }
  // epilogue: l lives at dim-80 column (n2=5, col=0 lane of each quad group)
  int src = lane & 48;
#pragma unroll
  for (int m = 0; m < 2; m++)
#pragma unroll
    for (int r = 0; r < 4; r++) {
      float l = __shfl(o[m][5][r], src);
      float inv = 1.f / l;
      int t = b * S_LEN + qw + m * 16 + quad * 4 + r;
#pragma unroll
      for (int n2 = 0; n2 < 5; n2++)
        Oo[(size_t)t * HID + h * DH + n2 * 16 + col] = f2b(o[m][n2][r] * inv);
    }
}

extern "C" void kernel_launch(void* const* d_in, const int* in_sizes, int n_in,
                              void* d_out, int out_size, void* d_ws, size_t ws_size,
                              hipStream_t stream) {
  const float* hidden  = (const float*)d_in[0];
  const float* cosd    = (const float*)d_in[1];
  const float* sind    = (const float*)d_in[2];
  const float* w_qkv   = (const float*)d_in[3];
  const float* b_qkv   = (const float*)d_in[4];
  const float* w_dense = (const float*)d_in[5];
  const float* b_dense = (const float*)d_in[6];
  float* out = (float*)d_out;

  // workspace layout (regions reused across phase boundaries):
  //  A: [0, 81.3MB)  = hid_bf + wqkv_bf, later reused as Q96
  //  B: [81.3, 207.1MB) = qkv_bf, later reused as attn_bf + wdense_bf
  //  C: [207.1, 257.4MB) = K96
  //  D: [257.4, 299.4MB) = Vt
  char* ws = (char*)d_ws;
  u16* hid_bf    = (u16*)(ws);
  u16* wqkv_bf   = (u16*)(ws + 41943040ull);
  u16* Q96       = (u16*)(ws);                                 // reuses A
  u16* qkv_bf    = (u16*)(ws + 81264640ull);
  u16* attn_bf   = (u16*)(ws + 81264640ull);                   // reuses B
  u16* wdense_bf = (u16*)(ws + 81264640ull + 41943040ull);     // reuses B tail
  u16* K96       = (u16*)(ws + 81264640ull + 125829120ull);
  u16* Vt        = (u16*)(ws + 81264640ull + 125829120ull + 50331648ull);

  cast_bf16_kernel<<<2048, 256, 0, stream>>>(hidden, hid_bf, T_LEN * HID / 4);
  cast_bf16_kernel<<<2048, 256, 0, stream>>>(w_qkv, wqkv_bf, NQKV * HID / 4);
  gemm256_kernel<1><<<dim3(NQKV / 256, T_LEN / 256), 512, 0, stream>>>(
      hid_bf, wqkv_bf, b_qkv, qkv_bf, T_LEN, NQKV, HID);
  rope_qk_kernel<<<T_LEN, 256, 0, stream>>>(qkv_bf, cosd, sind, Q96, K96);
  v_trans_kernel<<<4096, 256, 0, stream>>>(qkv_bf, Vt);
  flash_kernel<<<dim3(8, 256), 256, 0, stream>>>(Q96, K96, Vt, attn_bf);
  cast_bf16_kernel<<<512, 256, 0, stream>>>(w_dense, wdense_bf, HID * HID / 4);
  gemm256_kernel<0><<<dim3(HID / 256, T_LEN / 256), 512, 0, stream>>>(
      attn_bf, wdense_bf, b_dense, out, T_LEN, HID, HID);
}